// Round 17
// baseline (163.881 us; speedup 1.0000x reference)
//
#include <hip/hip_runtime.h>
#include <hip/hip_bf16.h>

#define D_MODEL 1024
#define ATT_DIM 64
#define BATCH 8
#define SEQ 2048
#define MROWS (BATCH * SEQ)  // 16384

typedef short bf16x8 __attribute__((ext_vector_type(8)));
typedef float f32x4 __attribute__((ext_vector_type(4)));

#define MFMA16(a, b, c) __builtin_amdgcn_mfma_f32_16x16x32_bf16((a), (b), (c), 0, 0, 0)

__device__ inline short f2bf(float f) {
    union { __hip_bfloat16 h; short s; } u;
    u.h = __float2bfloat16(f);  // RNE
    return u.s;
}

// pack two f32 -> one dword of 2 bf16 (RNE); lo in low half
__device__ __forceinline__ unsigned cvtpk(float lo, float hi) {
    unsigned r;
    asm("v_cvt_pk_bf16_f32 %0, %1, %2" : "=v"(r) : "v"(lo), "v"(hi));
    return r;
}

__device__ __forceinline__ void gload_lds16(const void* g, void* l) {
    __builtin_amdgcn_global_load_lds(
        (const __attribute__((address_space(1))) void*)g,
        (__attribute__((address_space(3))) void*)l, 16, 0, 0);
}

// ---------------------------------------------------------------------------
// K0: convert Wq,Wk,Wv fp32 -> bf16 workspace [3][64][1024].
// Wq pre-scaled by 1/64 (exact pow2) so MFMA output == scores.
// ---------------------------------------------------------------------------
__global__ __launch_bounds__(256) void wcvt_kernel(
    const float* __restrict__ Wq, const float* __restrict__ Wk,
    const float* __restrict__ Wv, short* __restrict__ Wbf)
{
    const int idx = blockIdx.x * 256 + threadIdx.x;   // 24576 threads
    const int per = ATT_DIM * D_MODEL;                // 65536
    const int base = idx * 8;
    const int mi = base / per;
    const int off = base - mi * per;
    const float* src = (mi == 0) ? Wq : (mi == 1 ? Wk : Wv);
    const float sc = (mi == 0) ? (1.0f / 64.0f) : 1.0f;
    const float4 a = *reinterpret_cast<const float4*>(src + off);
    const float4 b = *reinterpret_cast<const float4*>(src + off + 4);
    bf16x8 r;
    r[0] = f2bf(a.x * sc); r[1] = f2bf(a.y * sc);
    r[2] = f2bf(a.z * sc); r[3] = f2bf(a.w * sc);
    r[4] = f2bf(b.x * sc); r[5] = f2bf(b.y * sc);
    r[6] = f2bf(b.z * sc); r[7] = f2bf(b.w * sc);
    *reinterpret_cast<bf16x8*>(Wbf + base) = r;
}

// ---------------------------------------------------------------------------
// K1: projections, CONTIGUOUS-READ split-K variant.
// Block = 256 thr = 4 waves; 16 rows per block; wave w owns K-quarter
// [w*256,(w+1)*256). Staging: 16 gload_lds per wave, EACH covering one
// fully-contiguous 1 KB row-piece (64 lanes x 16 B, XOR-permuted within
// the same 1 KB span -> still one contiguous fetch). No cross-wave barrier
// before compute (wave reads only its own As[w]); own-wave vmcnt(0) +
// sched_barrier orders ds_read after gload_lds (rule #18). After compute:
// one __syncthreads + split-K reduce in LDS, wave 0 stores.
// W (bf16, L2-resident) read direct from global per fragment.
// ---------------------------------------------------------------------------
__global__ __launch_bounds__(256) void proj_mfma_kernel(
    const float* __restrict__ q, const float* __restrict__ k,
    const float* __restrict__ v, const short* __restrict__ Wbf,
    short* __restrict__ qp, short* __restrict__ kp, short* __restrict__ vpT)
{
    const int mat = blockIdx.y;  // 0:q 1:k 2:v
    const float* x = (mat == 0) ? q : (mat == 1 ? k : v);
    const short* W = Wbf + mat * ATT_DIM * D_MODEL;

    __shared__ float As[4][16][256];   // 64 KB: [wave][row][k-quarter], swizzled
    __shared__ float red[3][16][64];   // 12 KB: waves 1..3 partial sums

    const int tid = threadIdx.x;
    const int w = tid >> 6;    // 0..3 (K-quarter)
    const int l = tid & 63;
    const int lr = l & 15;
    const int g = l >> 4;

    const int m0 = blockIdx.x * 16;

    // ---- stage: 16 x 1KB contiguous instructions (one row-piece each) ----
    #pragma unroll
    for (int r = 0; r < 16; ++r) {
        const int cb = (l * 16) ^ ((r & 7) << 4);   // byte within the 1KB span
        gload_lds16(x + (long)(m0 + r) * D_MODEL + w * 256 + (cb >> 2),
                    &As[w][r][0]);
    }
    asm volatile("s_waitcnt vmcnt(0)" ::: "memory");
    __builtin_amdgcn_sched_barrier(0);

    // ---- compute: 32 MFMA over this wave's K-quarter ----
    f32x4 acc[4] = {};
    const int xr = (lr & 7) << 4;   // read-side XOR (bytes)
    const char* Ab = (const char*)&As[w][lr][0];
    #pragma unroll
    for (int ks = 0; ks < 8; ++ks) {
        const int b0 = ks * 128 + g * 32;
        const float4 a0 = *reinterpret_cast<const float4*>(Ab + (b0 ^ xr));
        const float4 a1 = *reinterpret_cast<const float4*>(Ab + ((b0 + 16) ^ xr));
        bf16x8 af;
        af[0] = f2bf(a0.x); af[1] = f2bf(a0.y); af[2] = f2bf(a0.z); af[3] = f2bf(a0.w);
        af[4] = f2bf(a1.x); af[5] = f2bf(a1.y); af[6] = f2bf(a1.z); af[7] = f2bf(a1.w);
        #pragma unroll
        for (int ef = 0; ef < 4; ++ef) {
            const bf16x8 wf = *reinterpret_cast<const bf16x8*>(
                W + (ef * 16 + lr) * D_MODEL + w * 256 + ks * 32 + g * 8);
            acc[ef] = MFMA16(af, wf, acc[ef]);
        }
    }

    // ---- split-K reduce ----
    if (w > 0) {
        #pragma unroll
        for (int ef = 0; ef < 4; ++ef)
            #pragma unroll
            for (int j = 0; j < 4; ++j)
                red[w - 1][g * 4 + j][ef * 16 + lr] = acc[ef][j];
    }
    __syncthreads();
    if (w != 0) return;

    #pragma unroll
    for (int ef = 0; ef < 4; ++ef)
        #pragma unroll
        for (int j = 0; j < 4; ++j)
            acc[ef][j] += red[0][g * 4 + j][ef * 16 + lr] +
                          red[1][g * 4 + j][ef * 16 + lr] +
                          red[2][g * 4 + j][ef * 16 + lr];

    // D layout: row = m0 + g*4 + j, col = lr (within 16-col tile ef)
    if (mat < 2) {
        short* out = (mat == 0) ? qp : kp;
        #pragma unroll
        for (int ef = 0; ef < 4; ++ef)
            #pragma unroll
            for (int j = 0; j < 4; ++j)
                out[(long)(m0 + g * 4 + j) * ATT_DIM + ef * 16 + lr] =
                    f2bf(acc[ef][j]);
    } else {
        const int b = m0 / SEQ;                   // 16-row block never straddles batch
        const int s0 = m0 - b * SEQ;
        #pragma unroll
        for (int ef = 0; ef < 4; ++ef)
            #pragma unroll
            for (int j = 0; j < 4; ++j)
                vpT[((long)b * ATT_DIM + ef * 16 + lr) * SEQ + s0 + g * 4 + j] =
                    f2bf(acc[ef][j]);
    }
}

// ---------------------------------------------------------------------------
// K2: fused scores+softmax+PV, swapped-QK^T register panel, shuffle-transpose.
// (byte-identical to rounds 10/13/14/16 — hardware-verified)
// ---------------------------------------------------------------------------
__global__ __launch_bounds__(512, 4) void attn_kernel(
    const short* __restrict__ qp, const short* __restrict__ kp,
    const short* __restrict__ vpT, float* __restrict__ probs,
    float* __restrict__ att)
{
    __shared__ float stats_l[8][16];
    __shared__ float lds_o[8][64][17];   // [wave][e][q]

    const int tid = threadIdx.x;
    const int w = tid >> 6;    // 0..7
    const int l = tid & 63;
    const int lr = l & 15;
    const int g = l >> 4;

    const int b = blockIdx.y;
    const int q0 = blockIdx.x * 16;

    const short* qpb = qp + ((long)b * SEQ + q0) * ATT_DIM;
    const short* kpb = kp + (long)b * SEQ * ATT_DIM;
    const short* vTb = vpT + (long)b * ATT_DIM * SEQ;

    const bf16x8 qa0 = *reinterpret_cast<const bf16x8*>(qpb + lr * ATT_DIM + g * 8);
    const bf16x8 qa1 = *reinterpret_cast<const bf16x8*>(qpb + lr * ATT_DIM + 32 + g * 8);

    const int kbeg = w * 256;

    // ---------------- pass A: swapped QK^T (pure loads+MFMA) ----------------
    f32x4 s[8][2];
    #pragma unroll
    for (int ch = 0; ch < 8; ++ch) {
        const short* kb = kpb + (long)(kbeg + ch * 32) * ATT_DIM;
        const bf16x8 kb00 = *reinterpret_cast<const bf16x8*>(kb + lr * ATT_DIM + g * 8);
        const bf16x8 kb01 = *reinterpret_cast<const bf16x8*>(kb + lr * ATT_DIM + 32 + g * 8);
        const bf16x8 kb10 = *reinterpret_cast<const bf16x8*>(kb + (16 + lr) * ATT_DIM + g * 8);
        const bf16x8 kb11 = *reinterpret_cast<const bf16x8*>(kb + (16 + lr) * ATT_DIM + 32 + g * 8);
        f32x4 t0 = {}; t0 = MFMA16(kb00, qa0, t0); t0 = MFMA16(kb01, qa1, t0);
        f32x4 t1 = {}; t1 = MFMA16(kb10, qa0, t1); t1 = MFMA16(kb11, qa1, t1);
        s[ch][0] = t0; s[ch][1] = t1;
    }

    // ---------------- softmax denominator (no max-sub; q = lr) --------------
    float lw = 0.f;
    #pragma unroll
    for (int ch = 0; ch < 8; ++ch)
        #pragma unroll
        for (int h = 0; h < 2; ++h)
            #pragma unroll
            for (int j = 0; j < 4; ++j) {
                const float e = __expf(s[ch][h][j]);
                s[ch][h][j] = e;
                lw += e;
            }
    lw += __shfl_xor(lw, 16);
    lw += __shfl_xor(lw, 32);

    if (l < 16) stats_l[w][l] = lw;
    __syncthreads();   // single softmax barrier

    float tot = 0.f;
    #pragma unroll
    for (int ww = 0; ww < 8; ++ww) tot += stats_l[ww][lr];
    const float inv = 1.0f / tot;
    #pragma unroll
    for (int ch = 0; ch < 8; ++ch)
        #pragma unroll
        for (int h = 0; h < 2; ++h)
            s[ch][h] *= inv;

    // ---------------- pass B: probs stores + shuffle-transpose + PV ---------
    f32x4 accO[4] = {};
    float* pbase = probs + ((long)b * SEQ + q0 + lr) * SEQ;   // row q = q0+lr
    const bool hi2 = (g & 2) != 0;
    const bool swp = ((g ^ (g >> 1)) & 1) != 0;
    const bool odd = (g & 1) != 0;

    #pragma unroll
    for (int ch = 0; ch < 8; ++ch) {
        const int k0 = kbeg + ch * 32;
        // direct vector stores of the normalized panel
        *reinterpret_cast<f32x4*>(pbase + k0 + g * 4)      = s[ch][0];
        *reinterpret_cast<f32x4*>(pbase + k0 + 16 + g * 4) = s[ch][1];

        // pack to bf16 pairs: xy = (P[4g..4g+3]), zw = (P[16+4g..16+4g+3])
        const unsigned xy0 = cvtpk(s[ch][0][0], s[ch][0][1]);
        const unsigned xy1 = cvtpk(s[ch][0][2], s[ch][0][3]);
        const unsigned zw0 = cvtpk(s[ch][1][0], s[ch][1][1]);
        const unsigned zw1 = cvtpk(s[ch][1][2], s[ch][1][3]);

        // 4x4 dword transpose among lanes {lr, lr+16, lr+32, lr+48}:
        const unsigned s1a = hi2 ? xy0 : zw0;
        const unsigned s1b = hi2 ? xy1 : zw1;
        const unsigned r1a = __shfl_xor(s1a, 32);
        const unsigned r1b = __shfl_xor(s1b, 32);
        const unsigned p1a = hi2 ? zw0 : xy0;   // own U[g][g>>1]
        const unsigned p1b = hi2 ? zw1 : xy1;
        const unsigned s2a = swp ? p1a : r1a;
        const unsigned s2b = swp ? p1b : r1b;
        const unsigned r2a = __shfl_xor(s2a, 16);
        const unsigned r2b = __shfl_xor(s2b, 16);
        const unsigned ka = swp ? r1a : p1a;    // kept unit
        const unsigned kb_ = swp ? r1b : p1b;
        const unsigned d0 = odd ? r2a : ka;
        const unsigned d1 = odd ? r2b : kb_;
        const unsigned d2 = odd ? ka : r2a;
        const unsigned d3 = odd ? kb_ : r2b;
        union { uint4 u4; bf16x8 v; } pbu;
        pbu.u4 = make_uint4(d0, d1, d2, d3);
        const bf16x8 pb = pbu.v;   // = P[k0+8g+i][q0+lr], i=0..7

        #pragma unroll
        for (int ef = 0; ef < 4; ++ef) {
            const bf16x8 va = *reinterpret_cast<const bf16x8*>(
                vTb + (long)(ef * 16 + lr) * SEQ + k0 + g * 8);
            accO[ef] = MFMA16(va, pb, accO[ef]);
        }
    }

    // ---------------- merge O across waves ----------------
    #pragma unroll
    for (int ef = 0; ef < 4; ++ef)
        #pragma unroll
        for (int j = 0; j < 4; ++j)
            lds_o[w][ef * 16 + g * 4 + j][lr] = accO[ef][j];
    __syncthreads();

    {
        const int qr = tid >> 5;          // 0..15
        const int e0 = (tid & 31) * 2;    // 0..62
        float o0 = 0.f, o1 = 0.f;
        #pragma unroll
        for (int ww = 0; ww < 8; ++ww) {
            o0 += lds_o[ww][e0][qr];
            o1 += lds_o[ww][e0 + 1][qr];
        }
        float2 o = make_float2(o0, o1);
        *reinterpret_cast<float2*>(att + ((long)b * SEQ + q0 + qr) * ATT_DIM + e0) = o;
    }
}

// ---------------------------------------------------------------------------
extern "C" void kernel_launch(void* const* d_in, const int* in_sizes, int n_in,
                              void* d_out, int out_size, void* d_ws, size_t ws_size,
                              hipStream_t stream)
{
    const float* q  = (const float*)d_in[0];
    const float* k  = (const float*)d_in[1];
    const float* v  = (const float*)d_in[2];
    const float* Wq = (const float*)d_in[3];
    const float* Wk = (const float*)d_in[4];
    const float* Wv = (const float*)d_in[5];

    float* att   = (float*)d_out;                        // [B,S,64]
    float* probs = att + (size_t)BATCH * SEQ * ATT_DIM;  // [B,S,S]

    short* qp  = (short*)d_ws;                    // [B*S,64] bf16 (Wq pre-scaled 1/64)
    short* kp  = qp + (size_t)MROWS * ATT_DIM;    // [B*S,64] bf16
    short* vpT = kp + (size_t)MROWS * ATT_DIM;    // [B][64][S] bf16
    short* Wbf = vpT + (size_t)MROWS * ATT_DIM;   // [3][64][1024] bf16

    wcvt_kernel<<<dim3(96), 256, 0, stream>>>(Wq, Wk, Wv, Wbf);

    proj_mfma_kernel<<<dim3(MROWS / 16, 3), 256, 0, stream>>>(
        q, k, v, Wbf, qp, kp, vpT);

    attn_kernel<<<dim3(SEQ / 16, BATCH), 512, 0, stream>>>(
        qp, kp, vpT, probs, att);
}

// Round 18
// 144.916 us; speedup vs baseline: 1.1309x; 1.1309x over previous
//
#include <hip/hip_runtime.h>
#include <hip/hip_bf16.h>

#define D_MODEL 1024
#define ATT_DIM 64
#define BATCH 8
#define SEQ 2048
#define MROWS (BATCH * SEQ)  // 16384

typedef short bf16x8 __attribute__((ext_vector_type(8)));
typedef float f32x4 __attribute__((ext_vector_type(4)));

#define MFMA16(a, b, c) __builtin_amdgcn_mfma_f32_16x16x32_bf16((a), (b), (c), 0, 0, 0)

__device__ inline short f2bf(float f) {
    union { __hip_bfloat16 h; short s; } u;
    u.h = __float2bfloat16(f);  // RNE
    return u.s;
}

// pack two f32 -> one dword of 2 bf16 (RNE); lo in low half
__device__ __forceinline__ unsigned cvtpk(float lo, float hi) {
    unsigned r;
    asm("v_cvt_pk_bf16_f32 %0, %1, %2" : "=v"(r) : "v"(lo), "v"(hi));
    return r;
}

__device__ __forceinline__ void gload_lds16(const void* g, void* l) {
    __builtin_amdgcn_global_load_lds(
        (const __attribute__((address_space(1))) void*)g,
        (__attribute__((address_space(3))) void*)l, 16, 0, 0);
}

// ---------------------------------------------------------------------------
// K0: convert Wq,Wk,Wv fp32 -> bf16 workspace [3][64][1024].
// Wq pre-scaled by 1/64 (exact pow2) so MFMA output == scores.
// ---------------------------------------------------------------------------
__global__ __launch_bounds__(256) void wcvt_kernel(
    const float* __restrict__ Wq, const float* __restrict__ Wk,
    const float* __restrict__ Wv, short* __restrict__ Wbf)
{
    const int idx = blockIdx.x * 256 + threadIdx.x;   // 24576 threads
    const int per = ATT_DIM * D_MODEL;                // 65536
    const int base = idx * 8;
    const int mi = base / per;
    const int off = base - mi * per;
    const float* src = (mi == 0) ? Wq : (mi == 1 ? Wk : Wv);
    const float sc = (mi == 0) ? (1.0f / 64.0f) : 1.0f;
    const float4 a = *reinterpret_cast<const float4*>(src + off);
    const float4 b = *reinterpret_cast<const float4*>(src + off + 4);
    bf16x8 r;
    r[0] = f2bf(a.x * sc); r[1] = f2bf(a.y * sc);
    r[2] = f2bf(a.z * sc); r[3] = f2bf(a.w * sc);
    r[4] = f2bf(b.x * sc); r[5] = f2bf(b.y * sc);
    r[6] = f2bf(b.z * sc); r[7] = f2bf(b.w * sc);
    *reinterpret_cast<bf16x8*>(Wbf + base) = r;
}

// ---------------------------------------------------------------------------
// K1: projections via MFMA with global_load_lds A-streaming.
// EXACT r16 form (measured-best of 8 proj variants; exploration closed).
// Block = 256 thr = 4 waves, 64 rows; K-chunks of 64 fp32, double-buffered
// LDS (2 x 16 KB); grid (MROWS/64, 3). A-tile XOR-swizzled on BOTH the
// global source (stage) and the ds_read (rule #21). W (bf16, L2-resident)
// read direct from global per fragment. V output stored transposed.
// ---------------------------------------------------------------------------
__global__ __launch_bounds__(256) void proj_mfma_kernel(
    const float* __restrict__ q, const float* __restrict__ k,
    const float* __restrict__ v, const short* __restrict__ Wbf,
    short* __restrict__ qp, short* __restrict__ kp, short* __restrict__ vpT)
{
    const int mat = blockIdx.y;  // 0:q 1:k 2:v
    const float* x = (mat == 0) ? q : (mat == 1 ? k : v);
    const short* W = Wbf + mat * ATT_DIM * D_MODEL;

    __shared__ float As[2][4096];   // [buf][64 rows x 64 cols], swizzled

    const int tid = threadIdx.x;
    const int w = tid >> 6;
    const int l = tid & 63;
    const int lr = l & 15;
    const int g = l >> 4;

    const int m0 = blockIdx.x * 64;
    const int row = w * 16 + lr;          // this lane's fragment row
    const int xr = (row & 7) << 4;        // read-side XOR (bytes)

    f32x4 acc[4] = {};

    // staging: wave w, issue j covers LDS bytes [(w*4+j)*1024, +1024)
    #define STAGE(c, buf)                                                      \
        {                                                                      \
            const int kt_ = (c) * 64;                                          \
            _Pragma("unroll")                                                  \
            for (int j = 0; j < 4; ++j) {                                      \
                const int rs = (w * 4 + j) * 4 + g;                            \
                const int scb = (lr * 16) ^ ((rs & 7) << 4);                   \
                gload_lds16(x + (long)(m0 + rs) * D_MODEL + kt_ + (scb >> 2),  \
                            &As[buf][(w * 4 + j) * 256]);                      \
            }                                                                  \
        }

    STAGE(0, 0);
    __syncthreads();

    for (int c = 0; c < 16; ++c) {
        const int buf = c & 1;
        if (c < 15) STAGE(c + 1, buf ^ 1);

        const int kt = c * 64;
        const char* Ab = (const char*)&As[buf][0] + row * 256;
        #pragma unroll
        for (int ks = 0; ks < 2; ++ks) {
            const int b0 = ks * 128 + g * 32;
            const float4 a0 = *reinterpret_cast<const float4*>(Ab + (b0 ^ xr));
            const float4 a1 = *reinterpret_cast<const float4*>(Ab + ((b0 + 16) ^ xr));
            bf16x8 af;
            af[0] = f2bf(a0.x); af[1] = f2bf(a0.y); af[2] = f2bf(a0.z); af[3] = f2bf(a0.w);
            af[4] = f2bf(a1.x); af[5] = f2bf(a1.y); af[6] = f2bf(a1.z); af[7] = f2bf(a1.w);
            #pragma unroll
            for (int ef = 0; ef < 4; ++ef) {
                const bf16x8 wf = *reinterpret_cast<const bf16x8*>(
                    W + (ef * 16 + lr) * D_MODEL + kt + ks * 32 + g * 8);
                acc[ef] = MFMA16(af, wf, acc[ef]);
            }
        }
        __syncthreads();   // drains vmcnt (stage c+1 landed) + read-done sync
    }
    #undef STAGE

    // D layout: row = m0 + w*16 + g*4 + j, col = lr (within 16-col tile ef)
    if (mat < 2) {
        short* out = (mat == 0) ? qp : kp;
        #pragma unroll
        for (int ef = 0; ef < 4; ++ef)
            #pragma unroll
            for (int j = 0; j < 4; ++j)
                out[(long)(m0 + w * 16 + g * 4 + j) * ATT_DIM + ef * 16 + lr] =
                    f2bf(acc[ef][j]);
    } else {
        const int b = m0 / SEQ;                   // 64-row block never straddles batch
        const int s0 = (m0 - b * SEQ) + w * 16;
        #pragma unroll
        for (int ef = 0; ef < 4; ++ef)
            #pragma unroll
            for (int j = 0; j < 4; ++j)
                vpT[((long)b * ATT_DIM + ef * 16 + lr) * SEQ + s0 + g * 4 + j] =
                    f2bf(acc[ef][j]);
    }
}

// ---------------------------------------------------------------------------
// K2: fused scores+softmax+PV — r10 structure with ONE change: probs stores
// are routed through a per-wave LDS panel and flushed as 512B-contiguous
// runs (store coalescing A/B). QK^T / softmax / shuffle-transpose / PV are
// byte-identical to the hardware-verified r10 kernel.
// Panel: [wave][16 rows][128 cols] f32, XOR-swizzled (byte ^= (row&7)<<4)
// to hit the 8-round bank floor on both b128 write and read. Wave-local
// (in-order DS per wave -> no barriers in the loop). Flushed twice
// (cols 0-127 after ch=3, cols 128-255 after ch=7): 8 instrs x 2 rows x
// 512 B contiguous each. Panel unioned with the O-merge buffer (+1 barrier
// before O-merge since u.o overlaps other waves' panels).
// ---------------------------------------------------------------------------
union AttnSmem {
    float panel[8][16][128];   // 64 KB: per-wave P store panel (swizzled)
    float o[8][64][17];        // 34.8 KB: [wave][e][q] for final merge
};

__global__ __launch_bounds__(512, 4) void attn_kernel(
    const short* __restrict__ qp, const short* __restrict__ kp,
    const short* __restrict__ vpT, float* __restrict__ probs,
    float* __restrict__ att)
{
    __shared__ __align__(16) AttnSmem u;
    __shared__ float stats_l[8][16];

    const int tid = threadIdx.x;
    const int w = tid >> 6;    // 0..7
    const int l = tid & 63;
    const int lr = l & 15;
    const int g = l >> 4;

    const int b = blockIdx.y;
    const int q0 = blockIdx.x * 16;

    const short* qpb = qp + ((long)b * SEQ + q0) * ATT_DIM;
    const short* kpb = kp + (long)b * SEQ * ATT_DIM;
    const short* vTb = vpT + (long)b * ATT_DIM * SEQ;

    const bf16x8 qa0 = *reinterpret_cast<const bf16x8*>(qpb + lr * ATT_DIM + g * 8);
    const bf16x8 qa1 = *reinterpret_cast<const bf16x8*>(qpb + lr * ATT_DIM + 32 + g * 8);

    const int kbeg = w * 256;

    // ---------------- pass A: swapped QK^T (pure loads+MFMA) ----------------
    f32x4 s[8][2];
    #pragma unroll
    for (int ch = 0; ch < 8; ++ch) {
        const short* kb = kpb + (long)(kbeg + ch * 32) * ATT_DIM;
        const bf16x8 kb00 = *reinterpret_cast<const bf16x8*>(kb + lr * ATT_DIM + g * 8);
        const bf16x8 kb01 = *reinterpret_cast<const bf16x8*>(kb + lr * ATT_DIM + 32 + g * 8);
        const bf16x8 kb10 = *reinterpret_cast<const bf16x8*>(kb + (16 + lr) * ATT_DIM + g * 8);
        const bf16x8 kb11 = *reinterpret_cast<const bf16x8*>(kb + (16 + lr) * ATT_DIM + 32 + g * 8);
        f32x4 t0 = {}; t0 = MFMA16(kb00, qa0, t0); t0 = MFMA16(kb01, qa1, t0);
        f32x4 t1 = {}; t1 = MFMA16(kb10, qa0, t1); t1 = MFMA16(kb11, qa1, t1);
        s[ch][0] = t0; s[ch][1] = t1;
    }

    // ---------------- softmax denominator (no max-sub; q = lr) --------------
    float lw = 0.f;
    #pragma unroll
    for (int ch = 0; ch < 8; ++ch)
        #pragma unroll
        for (int h = 0; h < 2; ++h)
            #pragma unroll
            for (int j = 0; j < 4; ++j) {
                const float e = __expf(s[ch][h][j]);
                s[ch][h][j] = e;
                lw += e;
            }
    lw += __shfl_xor(lw, 16);
    lw += __shfl_xor(lw, 32);

    if (l < 16) stats_l[w][l] = lw;
    __syncthreads();   // single softmax barrier

    float tot = 0.f;
    #pragma unroll
    for (int ww = 0; ww < 8; ++ww) tot += stats_l[ww][lr];
    const float inv = 1.0f / tot;
    #pragma unroll
    for (int ch = 0; ch < 8; ++ch)
        #pragma unroll
        for (int h = 0; h < 2; ++h)
            s[ch][h] *= inv;

    // ---------------- pass B: LDS-coalesced probs stores + PV ---------------
    f32x4 accO[4] = {};
    const bool hi2 = (g & 2) != 0;
    const bool swp = ((g ^ (g >> 1)) & 1) != 0;
    const bool odd = (g & 1) != 0;

    #pragma unroll
    for (int ch = 0; ch < 8; ++ch) {
        const int k0 = kbeg + ch * 32;

        // write normalized panel to LDS (swizzled; wave-local)
        {
            const int c0 = (ch & 3) * 32 + g * 4;       // col in 128-wide panel
            char* base = (char*)&u.panel[w][0][0] + lr * 512;
            *reinterpret_cast<f32x4*>(base + ((c0 * 4) ^ ((lr & 7) << 4))) = s[ch][0];
            *reinterpret_cast<f32x4*>(base + (((c0 + 16) * 4) ^ ((lr & 7) << 4))) = s[ch][1];
        }

        // pack to bf16 pairs: xy = (P[4g..4g+3]), zw = (P[16+4g..16+4g+3])
        const unsigned xy0 = cvtpk(s[ch][0][0], s[ch][0][1]);
        const unsigned xy1 = cvtpk(s[ch][0][2], s[ch][0][3]);
        const unsigned zw0 = cvtpk(s[ch][1][0], s[ch][1][1]);
        const unsigned zw1 = cvtpk(s[ch][1][2], s[ch][1][3]);

        // 4x4 dword transpose among lanes {lr, lr+16, lr+32, lr+48}:
        const unsigned s1a = hi2 ? xy0 : zw0;
        const unsigned s1b = hi2 ? xy1 : zw1;
        const unsigned r1a = __shfl_xor(s1a, 32);
        const unsigned r1b = __shfl_xor(s1b, 32);
        const unsigned p1a = hi2 ? zw0 : xy0;   // own U[g][g>>1]
        const unsigned p1b = hi2 ? zw1 : xy1;
        const unsigned s2a = swp ? p1a : r1a;
        const unsigned s2b = swp ? p1b : r1b;
        const unsigned r2a = __shfl_xor(s2a, 16);
        const unsigned r2b = __shfl_xor(s2b, 16);
        const unsigned ka = swp ? r1a : p1a;    // kept unit
        const unsigned kb_ = swp ? r1b : p1b;
        const unsigned d0 = odd ? r2a : ka;
        const unsigned d1 = odd ? r2b : kb_;
        const unsigned d2 = odd ? ka : r2a;
        const unsigned d3 = odd ? kb_ : r2b;
        union { uint4 u4; bf16x8 v; } pbu;
        pbu.u4 = make_uint4(d0, d1, d2, d3);
        const bf16x8 pb = pbu.v;   // = P[k0+8g+i][q0+lr], i=0..7

        #pragma unroll
        for (int ef = 0; ef < 4; ++ef) {
            const bf16x8 va = *reinterpret_cast<const bf16x8*>(
                vTb + (long)(ef * 16 + lr) * SEQ + k0 + g * 8);
            accO[ef] = MFMA16(va, pb, accO[ef]);
        }

        // flush half-panel as coalesced 512B runs (wave-local RAW via lgkmcnt)
        if ((ch & 3) == 3) {
            const int half = ch >> 2;
            #pragma unroll
            for (int j = 0; j < 8; ++j) {
                const int r = j * 2 + (l >> 5);
                const int cb = ((l & 31) * 16) ^ ((r & 7) << 4);
                const f32x4 val = *reinterpret_cast<const f32x4*>(
                    (const char*)&u.panel[w][0][0] + r * 512 + cb);
                *reinterpret_cast<f32x4*>(
                    probs + ((long)b * SEQ + q0 + r) * SEQ + kbeg + half * 128 +
                    (l & 31) * 4) = val;
            }
        }
    }

    // ---------------- merge O across waves ----------------
    __syncthreads();   // all panel reads done; union becomes u.o
    #pragma unroll
    for (int ef = 0; ef < 4; ++ef)
        #pragma unroll
        for (int j = 0; j < 4; ++j)
            u.o[w][ef * 16 + g * 4 + j][lr] = accO[ef][j];
    __syncthreads();

    {
        const int qr = tid >> 5;          // 0..15
        const int e0 = (tid & 31) * 2;    // 0..62
        float o0 = 0.f, o1 = 0.f;
        #pragma unroll
        for (int ww = 0; ww < 8; ++ww) {
            o0 += u.o[ww][e0][qr];
            o1 += u.o[ww][e0 + 1][qr];
        }
        float2 o = make_float2(o0, o1);
        *reinterpret_cast<float2*>(att + ((long)b * SEQ + q0 + qr) * ATT_DIM + e0) = o;
    }
}

// ---------------------------------------------------------------------------
extern "C" void kernel_launch(void* const* d_in, const int* in_sizes, int n_in,
                              void* d_out, int out_size, void* d_ws, size_t ws_size,
                              hipStream_t stream)
{
    const float* q  = (const float*)d_in[0];
    const float* k  = (const float*)d_in[1];
    const float* v  = (const float*)d_in[2];
    const float* Wq = (const float*)d_in[3];
    const float* Wk = (const float*)d_in[4];
    const float* Wv = (const float*)d_in[5];

    float* att   = (float*)d_out;                        // [B,S,64]
    float* probs = att + (size_t)BATCH * SEQ * ATT_DIM;  // [B,S,S]

    short* qp  = (short*)d_ws;                    // [B*S,64] bf16 (Wq pre-scaled 1/64)
    short* kp  = qp + (size_t)MROWS * ATT_DIM;    // [B*S,64] bf16
    short* vpT = kp + (size_t)MROWS * ATT_DIM;    // [B][64][S] bf16
    short* Wbf = vpT + (size_t)MROWS * ATT_DIM;   // [3][64][1024] bf16

    wcvt_kernel<<<dim3(96), 256, 0, stream>>>(Wq, Wk, Wv, Wbf);

    proj_mfma_kernel<<<dim3(MROWS / 64, 3), 256, 0, stream>>>(
        q, k, v, Wbf, qp, kp, vpT);

    attn_kernel<<<dim3(SEQ / 16, BATCH), 512, 0, stream>>>(
        qp, kp, vpT, probs, att);
}